// Round 26
// baseline (53.449 us; speedup 1.0000x reference)
//
#include <hip/hip_runtime.h>

// GaussianAntecedent: out[n,r] = mem[n,r] / (sum_r mem[n,r] + 1e-8)
// mem = exp2( -sum_d clamp(q*x+pn, +-K)^2 ),  K = sqrt(-log2(1e-8))
//   q = sqrt(0.5*log2 e)/(sigma+eps), pn = -c*q
//
// R25 post-mortem: invariant found -- every layout pays ~1.5cy/cell of
// broadcast-operand service on a shared pipe (X or constants), all tie
// ~30us. R26 eliminates broadcast MEMORY traffic entirely:
//  - lane = RULE: q/pn in 64 VGPRs (computed in-wave, one-time)
//  - each lane loads its OWN row coalesced (one vmcnt/wave)
//  - X broadcast via v_readlane (pure VALU on registers -> SGPRs;
//    each fma reads <=1 SGPR). No LDS anywhere. No setup kernel.
//  - DPP wave-sum (R5-validated) for the normalizer; per-row 256B
//    coalesced store.
// ~9.3k instr/wave, 1563 waves -> ~12us ideal makespan. If this still
// lands ~30us, the stall is NOT operand transport (VALUBusy decides).

constexpr int DDIM = 32;
constexpr int RR   = 64;

__device__ inline float fast_exp2(float x) {
#if __has_builtin(__builtin_amdgcn_exp2f)
    return __builtin_amdgcn_exp2f(x);
#else
    return exp2f(x);
#endif
}

template <int CTRL>
__device__ inline float dpp_add(float x) {
    int t = __builtin_amdgcn_update_dpp(0, __float_as_int(x), CTRL, 0xF, 0xF, true);
    return x + __int_as_float(t);
}

// Wave64 sum, result broadcast to all lanes via SGPR. [R5-validated]
__device__ inline float wave_sum_bcast(float x) {
    x = dpp_add<0x111>(x);  // row_shr:1
    x = dpp_add<0x112>(x);  // row_shr:2
    x = dpp_add<0x114>(x);  // row_shr:4
    x = dpp_add<0x118>(x);  // row_shr:8
    x = dpp_add<0x142>(x);  // row_bcast:15
    x = dpp_add<0x143>(x);  // row_bcast:31
    return __int_as_float(__builtin_amdgcn_readlane(__float_as_int(x), 63));
}

__device__ inline float rd_lane(float v, int i) {
    return __int_as_float(__builtin_amdgcn_readlane(__float_as_int(v), i));
}

__global__ __launch_bounds__(64) void gauss_main(
    const float* __restrict__ X,
    const float* __restrict__ centers,
    const float* __restrict__ sigma,
    float* __restrict__ out, int N)
{
    const int lane = threadIdx.x & 63;
    const int n0   = blockIdx.x * 64;      // this wave's 64 rows

    // ---- own row -> VGPRs (issued first; hides constant build) ----
    const int nown = n0 + lane;
    const int cown = (nown < N) ? nown : (N - 1);
    const float4* __restrict__ xp =
        reinterpret_cast<const float4*>(X + (size_t)cown * DDIM);
    float xr[DDIM];
    #pragma unroll
    for (int j = 0; j < 8; ++j) {
        float4 v = xp[j];
        xr[4*j+0] = v.x; xr[4*j+1] = v.y; xr[4*j+2] = v.z; xr[4*j+3] = v.w;
    }

    // ---- rule constants (rule = lane) -> VGPRs, computed once ----
    const float SQK = 0.84932180028801907f;   // sqrt(0.5 * log2(e))
    float q[DDIM], pn[DDIM];
    {
        const float4* __restrict__ cp =
            reinterpret_cast<const float4*>(centers + lane * DDIM);
        const float4* __restrict__ sp =
            reinterpret_cast<const float4*>(sigma + lane * DDIM);
        #pragma unroll
        for (int j = 0; j < 8; ++j) {
            float4 cc = cp[j], ss = sp[j];
            float q0 = SQK / (ss.x + 1e-8f);
            float q1 = SQK / (ss.y + 1e-8f);
            float q2 = SQK / (ss.z + 1e-8f);
            float q3 = SQK / (ss.w + 1e-8f);
            q[4*j+0] = q0; q[4*j+1] = q1; q[4*j+2] = q2; q[4*j+3] = q3;
            pn[4*j+0] = -cc.x * q0; pn[4*j+1] = -cc.y * q1;
            pn[4*j+2] = -cc.z * q2; pn[4*j+3] = -cc.w * q3;
        }
    }

    const float K = 5.1551357f;   // sqrt(26.575424759098897) = sqrt(-log2 1e-8)

    // ---- 64 rows; broadcast each row in-register via readlane ----
    for (int i = 0; i < 64; ++i) {
        // row i's x -> wave-uniform SGPRs (pure VALU, no memory)
        float sx[DDIM];
        #pragma unroll
        for (int d = 0; d < DDIM; ++d) sx[d] = rd_lane(xr[d], i);

        float A0 = 0.f, A1 = 0.f, A2 = 0.f, A3 = 0.f;
        #pragma unroll
        for (int d = 0; d < DDIM; d += 4) {
            float t0 = fmaf(q[d+0], sx[d+0], pn[d+0]);   // 1 SGPR operand
            float t1 = fmaf(q[d+1], sx[d+1], pn[d+1]);
            float t2 = fmaf(q[d+2], sx[d+2], pn[d+2]);
            float t3 = fmaf(q[d+3], sx[d+3], pn[d+3]);
            t0 = fminf(fmaxf(t0, -K), K);   // v_med3_f32
            t1 = fminf(fmaxf(t1, -K), K);
            t2 = fminf(fmaxf(t2, -K), K);
            t3 = fminf(fmaxf(t3, -K), K);
            A0 = fmaf(t0, -t0, A0);
            A1 = fmaf(t1, -t1, A1);
            A2 = fmaf(t2, -t2, A2);
            A3 = fmaf(t3, -t3, A3);
        }
        float mem = fast_exp2((A0 + A1) + (A2 + A3));

        float S = wave_sum_bcast(mem);
        const int row = n0 + i;
        if (row < N) {
            out[(size_t)row * RR + lane] = mem * __builtin_amdgcn_rcpf(S + 1e-8f);
        }
    }
}

extern "C" void kernel_launch(void* const* d_in, const int* in_sizes, int n_in,
                              void* d_out, int out_size, void* d_ws, size_t ws_size,
                              hipStream_t stream) {
    const float* X       = (const float*)d_in[0];
    const float* centers = (const float*)d_in[1];
    const float* sigma   = (const float*)d_in[2];
    float* out = (float*)d_out;

    const int N = in_sizes[0] / DDIM;      // 100000
    const int grid = (N + 63) / 64;        // 1563 single-wave blocks
    gauss_main<<<grid, 64, 0, stream>>>(X, centers, sigma, out, N);
}

// Round 27
// 28.637 us; speedup vs baseline: 1.8664x; 1.8664x over previous
//
#include <hip/hip_runtime.h>

// GaussianAntecedent: out[n,r] = mem[n,r] / (sum_r mem[n,r] + 1e-8)
// mem = exp2( -sum_d clamp(q*x+pn, +-K)^2 ),  K = sqrt(-log2(1e-8))
//   q = sqrt(0.5*log2 e)/(sigma+eps), pn = -c*q
//
// R26 post-mortem: readlane broadcast doubled VALU issue -- dead. Best
// stays R23 (29.4us). R27 attacks a defect present in ALL lane=row
// designs: the X row loads are STRIDED (64 lanes x 128B apart = 64 cache
// lines per wave-op vs 8 coalesced; 16 loads/wave x 12 waves/CU ~ 4-5us
// of serialized L1 transactions). Fix = GEMM-style staging:
//   coalesced global (4 float4/thread, linear) -> xsL pitch 33
//   (bank-rotated, conflict-free) -> per-lane register rows.
// xsL ALIASES memL (dead until rule loop) so LDS stays 52.6KB.
// Also: table divides via v_rcp_f32 (64 fewer instrs/thread; error
// ~1e-6 rel, absmax stays << threshold). Rest identical to R23.

typedef float v2f __attribute__((ext_vector_type(2)));

constexpr int DDIM = 32;
constexpr int RR   = 64;
constexpr int ROWS = 128;         // rows per block (2 per lane)
constexpr int MP   = 131;         // mem tile pitch; 524%32=12 (2-way reads)
constexpr int PP   = 5;           // partials pitch
constexpr int XP   = 33;          // X stage pitch: bank (row+d)%32, rotated

__device__ inline float fast_exp2(float x) {
#if __has_builtin(__builtin_amdgcn_exp2f)
    return __builtin_amdgcn_exp2f(x);
#else
    return exp2f(x);
#endif
}

__global__ __launch_bounds__(256, 2) void gauss_main(
    const float* __restrict__ X,
    const float* __restrict__ centers,
    const float* __restrict__ sigma,
    float* __restrict__ out, int N)
{
    __shared__ float tabL[RR * 64];       // 16 KB  [rule]{q[32]|pn[32]}
    __shared__ float bufL[RR * MP];       // 33.5 KB: xsL (first 16.9KB) then memL
    __shared__ float partL[ROWS * PP];    // 2.56 KB [row][wave]
    __shared__ float rsL[ROWS];           // 0.5 KB  rcp(S) per row
    float* xsL  = bufL;                   // [128][XP] staged X rows
    float* memL = bufL;                   // [rule][row] (after xsL is dead)

    const int tid  = threadIdx.x;
    const int lane = tid & 63;
    const int w    = tid >> 6;
    const int n0   = blockIdx.x * ROWS;

    // ---- coalesced X loads: 4 float4/thread, linear over the 16KB tile ----
    float4 xg[4];
    #pragma unroll
    for (int k = 0; k < 4; ++k) {
        const int f   = k * 256 + tid;       // float4 index 0..1023
        const int row = f >> 3;              // 0..127
        const int col = (f & 7) * 4;         // 0..28
        int rsrc = n0 + row; if (rsrc >= N) rsrc = N - 1;
        xg[k] = *reinterpret_cast<const float4*>(X + (size_t)rsrc * DDIM + col);
    }

    // ---- build q/pn table in LDS (rcpf: no slow f32 divide) ----
    const float SQK = 0.84932180028801907f;   // sqrt(0.5 * log2(e))
    #pragma unroll
    for (int i = 0; i < 8; ++i) {
        const int pi = tid * 8 + i;           // (rule, dim) pair 0..2047
        const int r  = pi >> 5, d = pi & 31;
        float q  = SQK * __builtin_amdgcn_rcpf(sigma[r * DDIM + d] + 1e-8f);
        tabL[r * 64 + d]        = q;
        tabL[r * 64 + DDIM + d] = -centers[r * DDIM + d] * q;
    }

    // ---- write staged X into xsL (pitch 33; ~2-way write conflicts) ----
    #pragma unroll
    for (int k = 0; k < 4; ++k) {
        const int f   = k * 256 + tid;
        const int row = f >> 3;
        const int col = (f & 7) * 4;
        xsL[row * XP + col + 0] = xg[k].x;
        xsL[row * XP + col + 1] = xg[k].y;
        xsL[row * XP + col + 2] = xg[k].z;
        xsL[row * XP + col + 3] = xg[k].w;
    }
    __syncthreads();   // bar1: xsL + tabL ready

    // ---- own 2 rows -> registers (bank-rotated, conflict-free reads) ----
    v2f xa2[16], xb2[16];
    #pragma unroll
    for (int p = 0; p < 16; ++p) {
        xa2[p] = (v2f){xsL[lane * XP + 2 * p], xsL[lane * XP + 2 * p + 1]};
        xb2[p] = (v2f){xsL[(64 + lane) * XP + 2 * p],
                       xsL[(64 + lane) * XP + 2 * p + 1]};
    }
    __syncthreads();   // bar2: xsL dead; memL may now be written

    const float K = 5.1551357f;   // sqrt(26.575424759098897) = sqrt(-log2 1e-8)
    float Sa = 0.f, Sb = 0.f;

    // ---- 16 rules for this wave; batched constant loads per rule ----
    #pragma unroll
    for (int rr = 0; rr < 16; ++rr) {
        const int r = w * 16 + rr;
        const float4* __restrict__ tp =
            reinterpret_cast<const float4*>(&tabL[r * 64]);

        float4 cf[16];
        #pragma unroll
        for (int j = 0; j < 16; ++j) cf[j] = tp[j];
        #pragma unroll
        for (int j = 0; j < 16; ++j)
            asm volatile("" :: "v"(cf[j].x), "v"(cf[j].y),
                               "v"(cf[j].z), "v"(cf[j].w));

        v2f Aa[2] = {{0.f,0.f},{0.f,0.f}};
        v2f Ab[2] = {{0.f,0.f},{0.f,0.f}};
        #pragma unroll
        for (int j = 0; j < 8; ++j) {
            float4 qf = cf[j];        // q  dims 4j..4j+3
            float4 pf = cf[8 + j];    // pn dims 4j..4j+3
            v2f q0 = {qf.x, qf.y}, q1 = {qf.z, qf.w};
            v2f p0 = {pf.x, pf.y}, p1 = {pf.z, pf.w};
            v2f ta0 = __builtin_elementwise_fma(q0, xa2[2*j],   p0);
            v2f ta1 = __builtin_elementwise_fma(q1, xa2[2*j+1], p1);
            v2f tb0 = __builtin_elementwise_fma(q0, xb2[2*j],   p0);
            v2f tb1 = __builtin_elementwise_fma(q1, xb2[2*j+1], p1);
            // clamp to [-K, K]: fminf(fmaxf(.)) fuses to v_med3_f32
            ta0.x = fminf(fmaxf(ta0.x, -K), K); ta0.y = fminf(fmaxf(ta0.y, -K), K);
            ta1.x = fminf(fmaxf(ta1.x, -K), K); ta1.y = fminf(fmaxf(ta1.y, -K), K);
            tb0.x = fminf(fmaxf(tb0.x, -K), K); tb0.y = fminf(fmaxf(tb0.y, -K), K);
            tb1.x = fminf(fmaxf(tb1.x, -K), K); tb1.y = fminf(fmaxf(tb1.y, -K), K);
            Aa[0] = __builtin_elementwise_fma(ta0, -ta0, Aa[0]);
            Aa[1] = __builtin_elementwise_fma(ta1, -ta1, Aa[1]);
            Ab[0] = __builtin_elementwise_fma(tb0, -tb0, Ab[0]);
            Ab[1] = __builtin_elementwise_fma(tb1, -tb1, Ab[1]);
        }
        v2f aa = Aa[0] + Aa[1];
        v2f ab = Ab[0] + Ab[1];
        float ma = fast_exp2(aa.x + aa.y);
        float mb = fast_exp2(ab.x + ab.y);
        Sa += ma;
        Sb += mb;
        memL[r * MP + lane]      = ma;   // stride-1 across lanes: clean
        memL[r * MP + 64 + lane] = mb;
    }
    partL[lane * PP + w]        = Sa;    // (5*lane+w)%32: 2-way, free
    partL[(64 + lane) * PP + w] = Sb;

    __syncthreads();   // bar3: mem tile + partials ready

    if (tid < ROWS) {
        float s = partL[tid * PP + 0] + partL[tid * PP + 1] +
                  partL[tid * PP + 2] + partL[tid * PP + 3];
        rsL[tid] = __builtin_amdgcn_rcpf(s + 1e-8f);
    }
    __syncthreads();   // bar4: rs ready

    // ---- epilogue: contiguous 4KB-per-step float4 stores ----
    const int nvalid = N - n0;   // rows in this block (128 except last)
    #pragma unroll
    for (int ch = 0; ch < 8; ++ch) {
        const int f4  = ch * 256 + tid;       // 0..2047
        const int row = f4 >> 4;              // 0..127
        const int r4  = (f4 & 15) * 4;        // rule quad base
        if (row < nvalid) {
            float rs = rsL[row];
            float4 o;
            o.x = memL[(r4 + 0) * MP + row] * rs;
            o.y = memL[(r4 + 1) * MP + row] * rs;
            o.z = memL[(r4 + 2) * MP + row] * rs;
            o.w = memL[(r4 + 3) * MP + row] * rs;
            *reinterpret_cast<float4*>(&out[(size_t)(n0 + row) * RR + r4]) = o;
        }
    }
}

extern "C" void kernel_launch(void* const* d_in, const int* in_sizes, int n_in,
                              void* d_out, int out_size, void* d_ws, size_t ws_size,
                              hipStream_t stream) {
    const float* X       = (const float*)d_in[0];
    const float* centers = (const float*)d_in[1];
    const float* sigma   = (const float*)d_in[2];
    float* out = (float*)d_out;

    const int N = in_sizes[0] / DDIM;  // 100000
    const int grid = (N + ROWS - 1) / ROWS;   // 782
    gauss_main<<<grid, 256, 0, stream>>>(X, centers, sigma, out, N);
}

// Round 28
// 28.398 us; speedup vs baseline: 1.8821x; 1.0084x over previous
//
#include <hip/hip_runtime.h>

// GaussianAntecedent: out[n,r] = mem[n,r] / (sum_r mem[n,r] + 1e-8)
// mem = exp2( -sum_d clamp(q*x+pn, +-K)^2 ),  K = sqrt(-log2(1e-8))
//   q = sqrt(0.5*log2 e)/(sigma+eps), pn = -c*q
//
// R27 post-mortem: coalesced X staging +0.8us (28.6 best). VALU ~45%
// busy; rest = latency at 3 waves/SIMD. R28: occupancy 3->4 blocks/CU
// via LDS diet -- mem tile stored as BF16 (round-half-up; rel err 2^-9,
// absmax ~5e-8 vs 2.57e-7 threshold): memH 16.6KB fits INSIDE the xsL
// alias buffer. LDS 52.6 -> 35.5KB -> 4 blocks/CU (16 waves, +33%
// hiding). cf batch+pin dropped (R23: neutral) to fit VGPR<=128 under
// launch_bounds(256,4). Pitch 130 ushorts (word-pitch 65, odd): writes
// 2-way free, epilogue reads ~2-way.

typedef float v2f __attribute__((ext_vector_type(2)));

constexpr int DDIM = 32;
constexpr int RR   = 64;
constexpr int ROWS = 128;   // rows per block (2 per lane)
constexpr int PP   = 5;     // partials pitch (floats)
constexpr int XP   = 33;    // X stage pitch (floats)
constexpr int MPH  = 130;   // mem tile pitch (ushorts); word-pitch 65 (odd)

__device__ inline float fast_exp2(float x) {
#if __has_builtin(__builtin_amdgcn_exp2f)
    return __builtin_amdgcn_exp2f(x);
#else
    return exp2f(x);
#endif
}

__device__ inline unsigned short f2bf(float x) {
    return (unsigned short)((__float_as_uint(x) + 0x8000u) >> 16);
}
__device__ inline float bf2f(unsigned short h) {
    return __uint_as_float(((unsigned int)h) << 16);
}

__global__ __launch_bounds__(256, 4) void gauss_main(
    const float* __restrict__ X,
    const float* __restrict__ centers,
    const float* __restrict__ sigma,
    float* __restrict__ out, int N)
{
    __shared__ float tabL[RR * 64];        // 16 KB   [rule]{q[32]|pn[32]}
    __shared__ float bufL[ROWS * XP];      // 16.9 KB: xsL then memH (alias)
    __shared__ float partL[ROWS * PP];     // 2.56 KB [row][wave]
    __shared__ float rsL[ROWS];            // 0.5 KB  rcp(S) per row
    float* xsL = bufL;                             // [128][33] staged X
    unsigned short* memH = (unsigned short*)bufL;  // [64][130] bf16 mem

    const int tid  = threadIdx.x;
    const int lane = tid & 63;
    const int w    = tid >> 6;
    const int n0   = blockIdx.x * ROWS;

    // ---- coalesced X loads: 4 float4/thread, linear over the 16KB tile ----
    float4 xg[4];
    #pragma unroll
    for (int k = 0; k < 4; ++k) {
        const int f   = k * 256 + tid;       // float4 index 0..1023
        const int row = f >> 3;              // 0..127
        const int col = (f & 7) * 4;         // 0..28
        int rsrc = n0 + row; if (rsrc >= N) rsrc = N - 1;
        xg[k] = *reinterpret_cast<const float4*>(X + (size_t)rsrc * DDIM + col);
    }

    // ---- build q/pn table in LDS (rcpf: no slow f32 divide) ----
    const float SQK = 0.84932180028801907f;   // sqrt(0.5 * log2(e))
    #pragma unroll
    for (int i = 0; i < 8; ++i) {
        const int pi = tid * 8 + i;           // (rule, dim) pair 0..2047
        const int r  = pi >> 5, d = pi & 31;
        float q  = SQK * __builtin_amdgcn_rcpf(sigma[r * DDIM + d] + 1e-8f);
        tabL[r * 64 + d]        = q;
        tabL[r * 64 + DDIM + d] = -centers[r * DDIM + d] * q;
    }

    // ---- write staged X into xsL (pitch 33) ----
    #pragma unroll
    for (int k = 0; k < 4; ++k) {
        const int f   = k * 256 + tid;
        const int row = f >> 3;
        const int col = (f & 7) * 4;
        xsL[row * XP + col + 0] = xg[k].x;
        xsL[row * XP + col + 1] = xg[k].y;
        xsL[row * XP + col + 2] = xg[k].z;
        xsL[row * XP + col + 3] = xg[k].w;
    }
    __syncthreads();   // bar1: xsL + tabL ready

    // ---- own 2 rows -> registers (bank-rotated, conflict-free reads) ----
    v2f xa2[16], xb2[16];
    #pragma unroll
    for (int p = 0; p < 16; ++p) {
        xa2[p] = (v2f){xsL[lane * XP + 2 * p], xsL[lane * XP + 2 * p + 1]};
        xb2[p] = (v2f){xsL[(64 + lane) * XP + 2 * p],
                       xsL[(64 + lane) * XP + 2 * p + 1]};
    }
    __syncthreads();   // bar2: xsL dead; memH may now be written

    const float K = 5.1551357f;   // sqrt(26.575424759098897) = sqrt(-log2 1e-8)
    float Sa = 0.f, Sb = 0.f;

    // ---- 16 rules for this wave; both rows per constant read ----
    #pragma unroll
    for (int rr = 0; rr < 16; ++rr) {
        const int r = w * 16 + rr;
        const float4* __restrict__ tp =
            reinterpret_cast<const float4*>(&tabL[r * 64]);

        v2f Aa[2] = {{0.f,0.f},{0.f,0.f}};
        v2f Ab[2] = {{0.f,0.f},{0.f,0.f}};
        #pragma unroll
        for (int j = 0; j < 8; ++j) {
            float4 qf = tp[j];        // q  dims 4j..4j+3 (uniform broadcast)
            float4 pf = tp[8 + j];    // pn dims 4j..4j+3
            v2f q0 = {qf.x, qf.y}, q1 = {qf.z, qf.w};
            v2f p0 = {pf.x, pf.y}, p1 = {pf.z, pf.w};
            v2f ta0 = __builtin_elementwise_fma(q0, xa2[2*j],   p0);
            v2f ta1 = __builtin_elementwise_fma(q1, xa2[2*j+1], p1);
            v2f tb0 = __builtin_elementwise_fma(q0, xb2[2*j],   p0);
            v2f tb1 = __builtin_elementwise_fma(q1, xb2[2*j+1], p1);
            // clamp to [-K, K]: fminf(fmaxf(.)) fuses to v_med3_f32
            ta0.x = fminf(fmaxf(ta0.x, -K), K); ta0.y = fminf(fmaxf(ta0.y, -K), K);
            ta1.x = fminf(fmaxf(ta1.x, -K), K); ta1.y = fminf(fmaxf(ta1.y, -K), K);
            tb0.x = fminf(fmaxf(tb0.x, -K), K); tb0.y = fminf(fmaxf(tb0.y, -K), K);
            tb1.x = fminf(fmaxf(tb1.x, -K), K); tb1.y = fminf(fmaxf(tb1.y, -K), K);
            Aa[0] = __builtin_elementwise_fma(ta0, -ta0, Aa[0]);
            Aa[1] = __builtin_elementwise_fma(ta1, -ta1, Aa[1]);
            Ab[0] = __builtin_elementwise_fma(tb0, -tb0, Ab[0]);
            Ab[1] = __builtin_elementwise_fma(tb1, -tb1, Ab[1]);
        }
        v2f aa = Aa[0] + Aa[1];
        v2f ab = Ab[0] + Ab[1];
        float ma = fast_exp2(aa.x + aa.y);
        float mb = fast_exp2(ab.x + ab.y);
        Sa += ma;
        Sb += mb;
        memH[r * MPH + lane]      = f2bf(ma);   // 2B stride-1: 2-way, free
        memH[r * MPH + 64 + lane] = f2bf(mb);
    }
    partL[lane * PP + w]        = Sa;    // (5*lane+w)%32: 2-way, free
    partL[(64 + lane) * PP + w] = Sb;

    __syncthreads();   // bar3: mem tile + partials ready

    if (tid < ROWS) {
        float s = partL[tid * PP + 0] + partL[tid * PP + 1] +
                  partL[tid * PP + 2] + partL[tid * PP + 3];
        rsL[tid] = __builtin_amdgcn_rcpf(s + 1e-8f);
    }
    __syncthreads();   // bar4: rs ready

    // ---- epilogue: contiguous 4KB-per-step float4 stores ----
    const int nvalid = N - n0;   // rows in this block (128 except last)
    #pragma unroll
    for (int ch = 0; ch < 8; ++ch) {
        const int f4  = ch * 256 + tid;       // 0..2047
        const int row = f4 >> 4;              // 0..127
        const int r4  = (f4 & 15) * 4;        // rule quad base
        if (row < nvalid) {
            float rs = rsL[row];
            float4 o;
            o.x = bf2f(memH[(r4 + 0) * MPH + row]) * rs;
            o.y = bf2f(memH[(r4 + 1) * MPH + row]) * rs;
            o.z = bf2f(memH[(r4 + 2) * MPH + row]) * rs;
            o.w = bf2f(memH[(r4 + 3) * MPH + row]) * rs;
            *reinterpret_cast<float4*>(&out[(size_t)(n0 + row) * RR + r4]) = o;
        }
    }
}

extern "C" void kernel_launch(void* const* d_in, const int* in_sizes, int n_in,
                              void* d_out, int out_size, void* d_ws, size_t ws_size,
                              hipStream_t stream) {
    const float* X       = (const float*)d_in[0];
    const float* centers = (const float*)d_in[1];
    const float* sigma   = (const float*)d_in[2];
    float* out = (float*)d_out;

    const int N = in_sizes[0] / DDIM;  // 100000
    const int grid = (N + ROWS - 1) / ROWS;   // 782
    gauss_main<<<grid, 256, 0, stream>>>(X, centers, sigma, out, N);
}